// Round 4
// baseline (354.868 us; speedup 1.0000x reference)
//
#include <hip/hip_runtime.h>

typedef float f32x16 __attribute__((ext_vector_type(16)));
typedef short bf16x8 __attribute__((ext_vector_type(8)));
typedef unsigned int u32;

static __device__ __forceinline__ unsigned short f2bf(float f) {
  union { float f; unsigned int u; } v;
  v.f = f;
  return (unsigned short)((v.u + 0x7FFFu + ((v.u >> 16) & 1u)) >> 16);
}

// async 16B global->LDS (DMA). LDS dest = wave-uniform base + lane*16.
static __device__ __forceinline__ void gl_lds16(const unsigned short* g,
                                                unsigned short* l) {
  __builtin_amdgcn_global_load_lds(
      (const __attribute__((address_space(1))) u32*)g,
      (__attribute__((address_space(3))) u32*)l, 16, 0, 0);
}

// ---------------- weights: OIHW fp32 -> [tap][co][ci] bf16; +zero page ----
__global__ __launch_bounds__(256) void convert_weights(
    const float* __restrict__ W1, const float* __restrict__ W2,
    unsigned short* __restrict__ W1b, unsigned short* __restrict__ W2b,
    unsigned short* __restrict__ zp) {
  if (blockIdx.x == 1728) {
    uint4* z = (uint4*)zp;
    z[threadIdx.x] = make_uint4(0, 0, 0, 0);
    z[256 + threadIdx.x] = make_uint4(0, 0, 0, 0);
    return;
  }
  int i = blockIdx.x * 256 + threadIdx.x;
  if (i < 9 * 128 * 256) {
    int tap = i >> 15;
    int r = i & 32767;
    int co = r >> 8, ci = r & 255;
    W1b[i] = f2bf(W1[(co * 256 + ci) * 9 + tap]);
  } else {
    int j = i - 9 * 128 * 256;
    if (j < 9 * 128 * 128) {
      int tap = j >> 14;
      int r = j & 16383;
      int co = r >> 7, ci = r & 127;
      W2b[j] = f2bf(W2[(co * 128 + ci) * 9 + tap]);
    }
  }
}

// -------- NCHW fp32 row -> padded NHWC bf16 [8][128][130][256] ------------
__global__ __launch_bounds__(256) void transpose_to_bf16(
    const float* __restrict__ src, unsigned short* __restrict__ dst, int coff) {
  int row = blockIdx.x;  // b*128+y
  int b = row >> 7, y = row & 127;
  const float* s = src + (long)b * 128 * 16384 + (long)y * 128;
  unsigned short* d = dst + ((long)row * 130 + 1) * 256 + coff;
  for (int it = 0; it < 8; ++it) {
    int u = it * 256 + (int)threadIdx.x;
    int cig = u >> 7, px = u & 127;
    unsigned short pk[8];
#pragma unroll
    for (int e = 0; e < 8; ++e)
      pk[e] = f2bf(s[(long)(cig * 8 + e) * 16384 + px]);
    uint4 vv;
    vv.x = (unsigned)pk[0] | ((unsigned)pk[1] << 16);
    vv.y = (unsigned)pk[2] | ((unsigned)pk[3] << 16);
    vv.z = (unsigned)pk[4] | ((unsigned)pk[5] << 16);
    vv.w = (unsigned)pk[6] | ((unsigned)pk[7] << 16);
    *(uint4*)(&d[(long)px * 256 + cig * 8]) = vv;
  }
  if (coff == 0 && threadIdx.x < 64) {  // zero x-pad columns 0 and 129
    int colsel = threadIdx.x >> 5, k = threadIdx.x & 31;
    long col = colsel * 129L;
    *(uint4*)(&dst[((long)row * 130 + col) * 256 + k * 8]) = make_uint4(0, 0, 0, 0);
  }
}

// ---------------- 3x3 SAME conv, implicit GEMM, bf16 MFMA -----------------
// block = 2 image rows: 256 px x 128 co, 8 waves (wco 2 x wpx 4).
// Weights (A-frags) loaded global->regs per wave (L2-resident, af[9][2]).
// Input staged 16 ci/chunk into DOUBLE-BUFFERED plane-split LDS via
// global_load_lds; 2-phase pipeline: stage(k+1) issued before compute(k),
// single vmcnt-drain at the phase-end __syncthreads (T3-minimum).
#define IPL 520   // in-tile slots/plane (4 halo rows x 130)
template <int CIN, bool OUT_NCHW>
__global__ __launch_bounds__(512) void conv3x3(
    const unsigned short* __restrict__ src,  // padded NHWC [8][128][130][CIN]
    const unsigned short* __restrict__ wt,   // [9][128][CIN] bf16
    const float* __restrict__ bias,          // [128]
    const unsigned short* __restrict__ zp,   // zeroed 8KB
    unsigned short* __restrict__ dst_bf16,   // padded NHWC [8][128][130][128]
    float* __restrict__ dst_f32) {           // NCHW fp32 [8,128,128,128]
  constexpr int NC = CIN / 16;
  __shared__ unsigned short in_tile[2][2 * IPL * 8];  // 2 x 16.6KB
  __shared__ float sb[128];

  const int tid = threadIdx.x;
  const int b = blockIdx.x >> 6;
  const int y0 = (blockIdx.x & 63) * 2;
  const int lane = tid & 63, wave = tid >> 6;
  const int wco = wave & 1, wpx = wave >> 1;
  const int l31 = lane & 31, kh = lane >> 5;
  const int rowoff = wpx >> 1, p0 = (wpx & 1) * 64;

  if (tid < 128) sb[tid] = bias[tid];

  // staging geometry (wave-uniform)
  const int C0 = wave * 128;
  const int tp = tid >> 3, trr = tid & 7;           // tail decode (tid<16)
  const int thy = trr >> 1, thx = 128 + (trr & 1);
  const int tgy = y0 - 1 + thy;

#define STAGE_BULK(cic, bufi)                                                  \
  {                                                                            \
    _Pragma("unroll") for (int j = 0; j < 2; ++j) {                            \
      int C = C0 + j * 64;                                                     \
      int p = C >> 9, r = C & 511;                                             \
      int hy = r >> 7, hx0 = r & 127;                                          \
      int gy = y0 - 1 + hy;                                                    \
      const unsigned short* g =                                                \
          (gy >= 0 && gy < 128)                                                \
              ? src + ((long)(b * 128 + gy) * 130 + hx0 + lane) * CIN +        \
                    (cic)*16 + p * 8                                           \
              : zp + lane * 8;                                                 \
      gl_lds16(g, &in_tile[bufi][(size_t)(p * IPL + hy * 130 + hx0) * 8]);     \
    }                                                                          \
  }

#define LOAD_TAIL(cic, v)                                                      \
  {                                                                            \
    v = make_uint4(0, 0, 0, 0);                                                \
    if (tid < 16 && tgy >= 0 && tgy < 128)                                     \
      v = *(const uint4*)(src + ((long)(b * 128 + tgy) * 130 + thx) * CIN +    \
                          (cic)*16 + tp * 8);                                  \
  }

#define WRITE_TAIL(bufi, v)                                                    \
  {                                                                            \
    if (tid < 16)                                                              \
      *(uint4*)(&in_tile[bufi][(size_t)(tp * IPL + thy * 130 + thx) * 8]) = v; \
  }

  f32x16 acc[2][2] = {};

  // prologue: stage chunk 0 into buf 0
  uint4 tv;
  LOAD_TAIL(0, tv);
  STAGE_BULK(0, 0);
  WRITE_TAIL(0, tv);
  __syncthreads();

  const unsigned short* wbg = wt + (size_t)(wco * 64 + l31) * CIN + kh * 8;

  for (int cic = 0; cic < NC; ++cic) {
    const int cur = cic & 1;
    const bool more = (cic + 1 < NC);
    // 1) tail load for next chunk (oldest in vmcnt queue)
    uint4 tl = make_uint4(0, 0, 0, 0);
    if (more) LOAD_TAIL(cic + 1, tl);
    // 2) A-frag loads for this chunk (before gl_lds so their waits
    //    leave the prefetch in flight)
    bf16x8 af0[9], af1[9];
#pragma unroll
    for (int t = 0; t < 9; ++t) {
      af0[t] = *(const bf16x8*)(wbg + (size_t)(t * 128) * CIN + cic * 16);
      af1[t] = *(const bf16x8*)(wbg + (size_t)(t * 128 + 32) * CIN + cic * 16);
    }
    __builtin_amdgcn_sched_barrier(0);
    // 3) issue input prefetch for next chunk
    if (more) STAGE_BULK(cic + 1, cur ^ 1);
    // 4) compute this chunk
    const size_t ibase = (size_t)(kh * IPL) * 8;
    const unsigned short* it = in_tile[cur];
#pragma unroll
    for (int ky = 0; ky < 3; ++ky) {
      const int hy = ky + rowoff;
#pragma unroll
      for (int kx = 0; kx < 3; ++kx) {
        const int t = ky * 3 + kx;
        bf16x8 b0 = *(const bf16x8*)(&it[ibase + (size_t)(hy * 130 + p0 + l31 + kx) * 8]);
        bf16x8 b1 = *(const bf16x8*)(&it[ibase + (size_t)(hy * 130 + p0 + 32 + l31 + kx) * 8]);
        acc[0][0] = __builtin_amdgcn_mfma_f32_32x32x16_bf16(af0[t], b0, acc[0][0], 0, 0, 0);
        acc[0][1] = __builtin_amdgcn_mfma_f32_32x32x16_bf16(af0[t], b1, acc[0][1], 0, 0, 0);
        acc[1][0] = __builtin_amdgcn_mfma_f32_32x32x16_bf16(af1[t], b0, acc[1][0], 0, 0, 0);
        acc[1][1] = __builtin_amdgcn_mfma_f32_32x32x16_bf16(af1[t], b1, acc[1][1], 0, 0, 0);
      }
    }
    // 5) tail write for next chunk, then the single per-phase drain
    if (more) WRITE_TAIL(cur ^ 1, tl);
    __syncthreads();
  }

  // epilogue: bias + leaky. D layout: col(px)=lane&31, row(co)=(r&3)+8*(r>>2)+4*kh
  const int gyo = y0 + rowoff;
#pragma unroll
  for (int fc = 0; fc < 2; ++fc) {
#pragma unroll
    for (int fp = 0; fp < 2; ++fp) {
      const int px = p0 + fp * 32 + l31;
      if constexpr (!OUT_NCHW) {
#pragma unroll
        for (int rg = 0; rg < 4; ++rg) {
          const int co0 = wco * 64 + fc * 32 + rg * 8 + kh * 4;
          unsigned short pk[4];
#pragma unroll
          for (int q = 0; q < 4; ++q) {
            float v = acc[fc][fp][rg * 4 + q] + sb[co0 + q];
            v = v > 0.f ? v : 0.01f * v;
            pk[q] = f2bf(v);
          }
          uint2 o;
          o.x = (unsigned)pk[0] | ((unsigned)pk[1] << 16);
          o.y = (unsigned)pk[2] | ((unsigned)pk[3] << 16);
          *(uint2*)(&dst_bf16[((long)(b * 128 + gyo) * 130 + px + 1) * 128 + co0]) = o;
        }
      } else {
#pragma unroll
        for (int r = 0; r < 16; ++r) {
          const int co = wco * 64 + fc * 32 + (r & 3) + 8 * (r >> 2) + 4 * kh;
          float v = acc[fc][fp][r] + sb[co];
          v = v > 0.f ? v : 0.01f * v;
          dst_f32[((long)(b * 128 + co) << 14) + (gyo << 7) + px] = v;
        }
      }
    }
  }
  if constexpr (!OUT_NCHW) {  // zero x-pad cols 0,129 of this block's 2 rows
    if (tid < 64) {
      int row = tid >> 5, colsel = (tid >> 4) & 1, k = tid & 15;
      long col = colsel * 129L;
      *(uint4*)(&dst_bf16[((long)(b * 128 + y0 + row) * 130 + col) * 128 + k * 8]) =
          make_uint4(0, 0, 0, 0);
    }
  }
#undef STAGE_BULK
#undef LOAD_TAIL
#undef WRITE_TAIL
}

// ---------------- 1x1 conv to 2 classes + entropy map + unob --------------
__global__ __launch_bounds__(128) void ds_amap(
    const float* __restrict__ h, const float* __restrict__ wds,
    const int* __restrict__ tar, float* __restrict__ ds,
    float* __restrict__ amap) {
  __shared__ float w0[128], w1[128];
  int row = blockIdx.x;
  int b = row >> 7, y = row & 127;
  int px = threadIdx.x;
  w0[px] = wds[px];
  w1[px] = wds[128 + px];
  __syncthreads();
  const float* hp = h + (long)b * 128 * 16384 + y * 128 + px;
  float a0 = 0.f, a1 = 0.f;
#pragma unroll 16
  for (int c = 0; c < 128; ++c) {
    float v = hp[(long)c * 16384];
    a0 += w0[c] * v;
    a1 += w1[c] * v;
  }
  ds[((long)b * 2) * 16384 + y * 128 + px] = a0;
  ds[((long)b * 2 + 1) * 16384 + y * 128 + px] = a1;
  float m = fmaxf(a0, a1);
  float e0 = expf(a0 - m), e1 = expf(a1 - m);
  float s = e0 + e1;
  float p0 = e0 / s, p1 = e1 / s;
  float ent = -(p0 * log2f(p0 + 1e-6f) + p1 * log2f(p1 + 1e-6f));
  float un = ent >= 0.001f ? 1.f : 0.f;
  float pro = 1.f;
  const int* tb = tar + (long)b * 16384;
  if (y > 0 && y < 127 && px > 0 && px < 127) {
    int c = tb[y * 128 + px];
    if (c != 0) {
      int nb = tb[(y - 1) * 128 + px] + tb[(y + 1) * 128 + px] +
               tb[y * 128 + px - 1] + tb[y * 128 + px + 1];
      if (4 * c != nb) pro = 0.f;
    }
  }
  amap[(long)row * 128 + px] = un * pro;
}

extern "C" void kernel_launch(void* const* d_in, const int* in_sizes, int n_in,
                              void* d_out, int out_size, void* d_ws, size_t ws_size,
                              hipStream_t stream) {
  const float* x    = (const float*)d_in[0];
  const float* skip = (const float*)d_in[1];
  const int*   tar  = (const int*)d_in[2];
  const float* W1   = (const float*)d_in[3];
  const float* b1   = (const float*)d_in[4];
  const float* W2   = (const float*)d_in[5];
  const float* b2   = (const float*)d_in[6];
  const float* Wds  = (const float*)d_in[7];

  float* out_h  = (float*)d_out;            // 16777216 f32 (h, NCHW)
  float* out_ds = out_h + 16777216;         // 262144 f32
  float* out_am = out_ds + 262144;          // 131072 f32

  // ws: W1b | W2b | zp | (1MB) h1 (padded NHWC bf16 [8][128][130][128])
  unsigned short* W1b = (unsigned short*)d_ws;
  unsigned short* W2b = W1b + 294912;
  unsigned short* zp  = W2b + 147456;
  unsigned short* h1  = (unsigned short*)((char*)d_ws + (1u << 20));

  // h0: padded NHWC bf16 [8][128][130][256] = 68.2MB, lives in d_out;
  // fully dead before conv2 overwrites d_out with h.
  unsigned short* h0 = (unsigned short*)d_out;

  convert_weights<<<1729, 256, 0, stream>>>(W1, W2, W1b, W2b, zp);
  transpose_to_bf16<<<1024, 256, 0, stream>>>(x, h0, 0);
  transpose_to_bf16<<<1024, 256, 0, stream>>>(skip, h0, 128);
  conv3x3<256, false><<<512, 512, 0, stream>>>(h0, W1b, b1, zp, h1, nullptr);
  conv3x3<128, true><<<512, 512, 0, stream>>>(h1, W2b, b2, zp, nullptr, out_h);
  ds_amap<<<1024, 128, 0, stream>>>(out_h, Wds, tar, out_ds, out_am);
}

// Round 5
// 160.668 us; speedup vs baseline: 2.2087x; 2.2087x over previous
//
#include <hip/hip_runtime.h>

typedef float f32x16 __attribute__((ext_vector_type(16)));
typedef short bf16x8 __attribute__((ext_vector_type(8)));
typedef unsigned int u32;

static __device__ __forceinline__ unsigned short f2bf(float f) {
  union { float f; unsigned int u; } v;
  v.f = f;
  return (unsigned short)((v.u + 0x7FFFu + ((v.u >> 16) & 1u)) >> 16);
}

// async 16B global->LDS (DMA). LDS dest = wave-uniform base + lane*16.
static __device__ __forceinline__ void gl_lds16(const unsigned short* g,
                                                unsigned short* l) {
  __builtin_amdgcn_global_load_lds(
      (const __attribute__((address_space(1))) u32*)g,
      (__attribute__((address_space(3))) u32*)l, 16, 0, 0);
}

// ---- weights: OIHW fp32 -> [cic][p][tap][co][8ci] bf16 (contiguous 36KB
// per-chunk slab whose linear order == plane-split LDS layout); + zero page.
__global__ __launch_bounds__(256) void convert_weights(
    const float* __restrict__ W1, const float* __restrict__ W2,
    unsigned short* __restrict__ W1b, unsigned short* __restrict__ W2b,
    unsigned short* __restrict__ zp) {
  if (blockIdx.x == 1728) {
    uint4* z = (uint4*)zp;
    z[threadIdx.x] = make_uint4(0, 0, 0, 0);
    z[256 + threadIdx.x] = make_uint4(0, 0, 0, 0);
    return;
  }
  int i = blockIdx.x * 256 + threadIdx.x;
  if (i < 294912) {
    int e = i & 7, co = (i >> 3) & 127, r = i >> 10;  // r=(cic*2+p)*9+tap
    int tap = r % 9, pc = r / 9;
    int ci = (pc >> 1) * 16 + (pc & 1) * 8 + e;
    W1b[i] = f2bf(W1[(co * 256 + ci) * 9 + tap]);
  } else {
    int j = i - 294912;
    if (j < 147456) {
      int e = j & 7, co = (j >> 3) & 127, r = j >> 10;
      int tap = r % 9, pc = r / 9;
      int ci = (pc >> 1) * 16 + (pc & 1) * 8 + e;
      W2b[j] = f2bf(W2[(co * 128 + ci) * 9 + tap]);
    }
  }
}

// -- NCHW fp32 -> padded plane-major bf16 [8][128][32 cig][130 px][8 ci] ----
__global__ __launch_bounds__(256) void transpose_to_bf16(
    const float* __restrict__ src, unsigned short* __restrict__ dst, int cigb) {
  int row = blockIdx.x;  // b*128+y
  int b = row >> 7, y = row & 127;
  const float* s = src + (long)b * 128 * 16384 + (long)y * 128;
  for (int it = 0; it < 8; ++it) {
    int u = it * 256 + (int)threadIdx.x;
    int cig = u >> 7, px = u & 127;
    unsigned short pk[8];
#pragma unroll
    for (int e = 0; e < 8; ++e)
      pk[e] = f2bf(s[(long)(cig * 8 + e) * 16384 + px]);
    uint4 vv;
    vv.x = (unsigned)pk[0] | ((unsigned)pk[1] << 16);
    vv.y = (unsigned)pk[2] | ((unsigned)pk[3] << 16);
    vv.z = (unsigned)pk[4] | ((unsigned)pk[5] << 16);
    vv.w = (unsigned)pk[6] | ((unsigned)pk[7] << 16);
    *(uint4*)(&dst[(((long)row * 32 + cigb + cig) * 130 + px + 1) * 8]) = vv;
  }
  if (cigb == 0 && threadIdx.x < 64) {  // zero px 0,129 for all 32 cig
    int g = threadIdx.x >> 1;
    long col = (threadIdx.x & 1) * 129L;
    *(uint4*)(&dst[(((long)row * 32 + g) * 130 + col) * 8]) = make_uint4(0, 0, 0, 0);
  }
}

// ---------------- 3x3 SAME conv, implicit GEMM, bf16 MFMA -----------------
// block = 2 image rows: 256 px x 128 co, 8 waves (wco 2 x wpx 4).
// All staging via global_load_lds with CONTIGUOUS global streams:
//  - input [b][y][cig][130][8]: per (halo-row, plane) a 130x16B run
//  - weights [cic][p][tap][co][8]: per-chunk 36KB slab, linear==LDS order
#define IPL 520   // in-tile slots/plane (4 halo rows x 130)
#define WPL 1152  // wt-tile slots/plane (9 taps x 128 co)
template <int CIN, bool OUT_NCHW>
__global__ __launch_bounds__(512) void conv3x3(
    const unsigned short* __restrict__ src,  // [8][128][CIN/8][130][8]
    const unsigned short* __restrict__ wt,   // [cic][p][tap][co][8]
    const float* __restrict__ bias,          // [128]
    const unsigned short* __restrict__ zp,   // zeroed 8KB
    unsigned short* __restrict__ dst_bf16,   // [8][128][16][130][8]
    float* __restrict__ dst_f32) {           // NCHW fp32 [8,128,128,128]
  constexpr int CPG = CIN / 8;   // ci-groups per pixel row
  constexpr int NC = CIN / 16;   // K chunks
  __shared__ unsigned short in_tile[2 * IPL * 8];  // 16.6KB
  __shared__ unsigned short wt_tile[2 * WPL * 8];  // 36.9KB
  __shared__ float sb[128];

  const int tid = threadIdx.x;
  const int b = blockIdx.x >> 6;
  const int y0 = (blockIdx.x & 63) * 2;
  const int lane = tid & 63, wave = tid >> 6;
  const int wco = wave & 1, wpx = wave >> 1;
  const int l31 = lane & 31, kh = lane >> 5;
  const int rowoff = wpx >> 1, p0 = (wpx & 1) * 64;

  if (tid < 128) sb[tid] = bias[tid];

  // input staging geometry: segment = (halo-row shy, plane sp), one per wave
  const int shy = wave >> 1, sp = wave & 1;
  const int sgy = y0 - 1 + shy;
  const bool sok = (sgy >= 0 && sgy < 128);
  const unsigned short* srow =
      sok ? src + ((long)((b * 128 + sgy) * CPG) + sp) * 1040 : zp;
  // tail decode (tid<16): segment tid>>1, px 128/129
  const int tseg = tid >> 1, thx = 128 + (tid & 1);
  const int tp = tseg & 1, thy = tseg >> 1;
  const int tgy = y0 - 1 + thy;

  f32x16 acc[2][2] = {};

  for (int cic = 0; cic < NC; ++cic) {
    __syncthreads();
    // ---- weight slab: 36 contiguous 1KB ops, round-robin over waves
    const unsigned short* wslab = wt + (long)cic * 18432;
#pragma unroll
    for (int o = wave; o < 36; o += 8)
      gl_lds16(wslab + (o * 64 + lane) * 8, &wt_tile[(size_t)(o * 64) * 8]);
    // ---- input: 2 contiguous 1KB ops per wave (segment rows)
#pragma unroll
    for (int j = 0; j < 2; ++j)
      gl_lds16(srow + (sok ? ((long)cic * 2 * 1040 + (j * 64 + lane) * 8)
                           : (long)(lane * 8)),
               &in_tile[(size_t)(sp * IPL + shy * 130 + j * 64) * 8]);
    // ---- input tail: px 128,129 (16 chunks), reg-staged
    if (tid < 16) {
      uint4 v = make_uint4(0, 0, 0, 0);
      if (tgy >= 0 && tgy < 128)
        v = *(const uint4*)(src + ((long)((b * 128 + tgy) * CPG) + cic * 2 + tp) * 1040 +
                            thx * 8);
      *(uint4*)(&in_tile[(size_t)(tp * IPL + thy * 130 + thx) * 8]) = v;
    }
    __syncthreads();

    const size_t ibase = (size_t)(kh * IPL) * 8;
    const size_t wbase = (size_t)(kh * WPL) * 8;
#pragma unroll
    for (int ky = 0; ky < 3; ++ky) {
      const int hy = ky + rowoff;
#pragma unroll
      for (int kx = 0; kx < 3; ++kx) {
        const int t = ky * 3 + kx;
        bf16x8 a0 = *(const bf16x8*)(&wt_tile[wbase + (size_t)(t * 128 + wco * 64 + l31) * 8]);
        bf16x8 a1 = *(const bf16x8*)(&wt_tile[wbase + (size_t)(t * 128 + wco * 64 + 32 + l31) * 8]);
        bf16x8 b0 = *(const bf16x8*)(&in_tile[ibase + (size_t)(hy * 130 + p0 + l31 + kx) * 8]);
        bf16x8 b1 = *(const bf16x8*)(&in_tile[ibase + (size_t)(hy * 130 + p0 + 32 + l31 + kx) * 8]);
        acc[0][0] = __builtin_amdgcn_mfma_f32_32x32x16_bf16(a0, b0, acc[0][0], 0, 0, 0);
        acc[0][1] = __builtin_amdgcn_mfma_f32_32x32x16_bf16(a0, b1, acc[0][1], 0, 0, 0);
        acc[1][0] = __builtin_amdgcn_mfma_f32_32x32x16_bf16(a1, b0, acc[1][0], 0, 0, 0);
        acc[1][1] = __builtin_amdgcn_mfma_f32_32x32x16_bf16(a1, b1, acc[1][1], 0, 0, 0);
      }
    }
  }

  // epilogue: bias + leaky. D layout: col(px)=lane&31, row(co)=(r&3)+8*(r>>2)+4*kh
  const int gyo = y0 + rowoff;
#pragma unroll
  for (int fc = 0; fc < 2; ++fc) {
#pragma unroll
    for (int fp = 0; fp < 2; ++fp) {
      const int px = p0 + fp * 32 + l31;
      if constexpr (!OUT_NCHW) {
#pragma unroll
        for (int rg = 0; rg < 4; ++rg) {
          const int co0 = wco * 64 + fc * 32 + rg * 8 + kh * 4;
          unsigned short pk[4];
#pragma unroll
          for (int q = 0; q < 4; ++q) {
            float v = acc[fc][fp][rg * 4 + q] + sb[co0 + q];
            v = v > 0.f ? v : 0.01f * v;
            pk[q] = f2bf(v);
          }
          uint2 o;
          o.x = (unsigned)pk[0] | ((unsigned)pk[1] << 16);
          o.y = (unsigned)pk[2] | ((unsigned)pk[3] << 16);
          // dst [b][y][co/8][130][8], within-chunk offset kh*4
          *(uint2*)(&dst_bf16[(((long)(b * 128 + gyo) * 16 + (co0 >> 3)) * 130 + px + 1) * 8 +
                              kh * 4]) = o;
        }
      } else {
#pragma unroll
        for (int r = 0; r < 16; ++r) {
          const int co = wco * 64 + fc * 32 + (r & 3) + 8 * (r >> 2) + 4 * kh;
          float v = acc[fc][fp][r] + sb[co];
          v = v > 0.f ? v : 0.01f * v;
          dst_f32[((long)(b * 128 + co) << 14) + (gyo << 7) + px] = v;
        }
      }
    }
  }
  if constexpr (!OUT_NCHW) {  // zero px 0,129 of this block's 2 rows, all cig
    if (tid < 64) {
      int row = tid >> 5, g = (tid >> 1) & 15;
      long col = (tid & 1) * 129L;
      *(uint4*)(&dst_bf16[(((long)(b * 128 + y0 + row) * 16 + g) * 130 + col) * 8]) =
          make_uint4(0, 0, 0, 0);
    }
  }
}

// ---------------- 1x1 conv to 2 classes + entropy map + unob --------------
__global__ __launch_bounds__(128) void ds_amap(
    const float* __restrict__ h, const float* __restrict__ wds,
    const int* __restrict__ tar, float* __restrict__ ds,
    float* __restrict__ amap) {
  __shared__ float w0[128], w1[128];
  int row = blockIdx.x;
  int b = row >> 7, y = row & 127;
  int px = threadIdx.x;
  w0[px] = wds[px];
  w1[px] = wds[128 + px];
  __syncthreads();
  const float* hp = h + (long)b * 128 * 16384 + y * 128 + px;
  float a0 = 0.f, a1 = 0.f;
#pragma unroll 16
  for (int c = 0; c < 128; ++c) {
    float v = hp[(long)c * 16384];
    a0 += w0[c] * v;
    a1 += w1[c] * v;
  }
  ds[((long)b * 2) * 16384 + y * 128 + px] = a0;
  ds[((long)b * 2 + 1) * 16384 + y * 128 + px] = a1;
  float m = fmaxf(a0, a1);
  float e0 = expf(a0 - m), e1 = expf(a1 - m);
  float s = e0 + e1;
  float p0 = e0 / s, p1 = e1 / s;
  float ent = -(p0 * log2f(p0 + 1e-6f) + p1 * log2f(p1 + 1e-6f));
  float un = ent >= 0.001f ? 1.f : 0.f;
  float pro = 1.f;
  const int* tb = tar + (long)b * 16384;
  if (y > 0 && y < 127 && px > 0 && px < 127) {
    int c = tb[y * 128 + px];
    if (c != 0) {
      int nb = tb[(y - 1) * 128 + px] + tb[(y + 1) * 128 + px] +
               tb[y * 128 + px - 1] + tb[y * 128 + px + 1];
      if (4 * c != nb) pro = 0.f;
    }
  }
  amap[(long)row * 128 + px] = un * pro;
}

extern "C" void kernel_launch(void* const* d_in, const int* in_sizes, int n_in,
                              void* d_out, int out_size, void* d_ws, size_t ws_size,
                              hipStream_t stream) {
  const float* x    = (const float*)d_in[0];
  const float* skip = (const float*)d_in[1];
  const int*   tar  = (const int*)d_in[2];
  const float* W1   = (const float*)d_in[3];
  const float* b1   = (const float*)d_in[4];
  const float* W2   = (const float*)d_in[5];
  const float* b2   = (const float*)d_in[6];
  const float* Wds  = (const float*)d_in[7];

  float* out_h  = (float*)d_out;            // 16777216 f32 (h, NCHW)
  float* out_ds = out_h + 16777216;         // 262144 f32
  float* out_am = out_ds + 262144;          // 131072 f32

  // ws: W1b | W2b | zp | (1MB) h1  [8][128][16][130][8] bf16 (34.1MB)
  unsigned short* W1b = (unsigned short*)d_ws;
  unsigned short* W2b = W1b + 294912;
  unsigned short* zp  = W2b + 147456;
  unsigned short* h1  = (unsigned short*)((char*)d_ws + (1u << 20));

  // h0: [8][128][32][130][8] bf16 = 68.2MB, lives in d_out (68.7MB);
  // fully dead before conv2 overwrites d_out with h.
  unsigned short* h0 = (unsigned short*)d_out;

  convert_weights<<<1729, 256, 0, stream>>>(W1, W2, W1b, W2b, zp);
  transpose_to_bf16<<<1024, 256, 0, stream>>>(x, h0, 0);
  transpose_to_bf16<<<1024, 256, 0, stream>>>(skip, h0, 16);
  conv3x3<256, false><<<512, 512, 0, stream>>>(h0, W1b, b1, zp, h1, nullptr);
  conv3x3<128, true><<<512, 512, 0, stream>>>(h1, W2b, b2, zp, nullptr, out_h);
  ds_amap<<<1024, 128, 0, stream>>>(out_h, Wds, tar, out_ds, out_am);
}